// Round 1
// baseline (177.638 us; speedup 1.0000x reference)
//
#include <hip/hip_runtime.h>

// Problem constants: T=16, H=1280, W=1280, N=64 boxes.
#define TT 16
#define HH 1280
#define WW 1280
#define NBOX 64
#define W4 (WW / 4)             // 320 float4 per row
#define SLICE4 (HH * W4)        // 409600 float4 per T-slice
#define TSPLIT 2                // grid covers T in 2 halves
#define TPT (TT / TSPLIT)       // 8 slices per thread

typedef float f32x4 __attribute__((ext_vector_type(4)));

// K1: build row/col membership bitmasks (one bit per box) in d_ws, and
// zero the output scalar (replaces the separate 4-byte hipMemsetAsync —
// stream order guarantees this lands before any K2 atomicAdd).
__global__ void build_masks_kernel(const int* __restrict__ boxes,
                                   unsigned long long* __restrict__ rowmask,
                                   unsigned long long* __restrict__ colmask,
                                   float* __restrict__ out) {
    __shared__ int bx1[NBOX], by1[NBOX], bx2[NBOX], by2[NBOX];
    int tid = threadIdx.x;
    if (tid < NBOX) {
        int4 b = ((const int4*)boxes)[tid];   // (x1, y1, x2, y2)
        bx1[tid] = b.x; by1[tid] = b.y; bx2[tid] = b.z; by2[tid] = b.w;
    }
    if (blockIdx.x == 0 && tid == 0) *out = 0.f;
    __syncthreads();
    int g = blockIdx.x * 256 + tid;           // 0..2559
    if (g < HH) {
        int y = g;
        unsigned long long m = 0ull;
#pragma unroll
        for (int b = 0; b < NBOX; ++b)
            if (by1[b] <= y && y < by2[b]) m |= (1ull << b);
        rowmask[y] = m;
    } else if (g < HH + WW) {
        int x = g - HH;
        unsigned long long m = 0ull;
#pragma unroll
        for (int b = 0; b < NBOX; ++b)
            if (bx1[b] <= x && x < bx2[b]) m |= (1ull << b);
        colmask[x] = m;
    }
}

// K2: R8's forced-MLP structure, T split by 2.
//  - v[8] batch (32 VGPRs live) instead of v[16] (64): VGPR ~100 -> ~64,
//    residency 5 -> up to 8 waves/SIMD.
//  - 3200 blocks (12.5/CU) instead of 1600 (6.25/CU): tail imbalance
//    ~12% -> ~4%. Block 0..1599 -> t=0..7, 1600..3199 -> t=8..15
//    (no intra-block tz divergence: SLICE4 is an exact block multiple).
//  - nontemporal loads: data is read exactly once; skip L2 allocate.
//  - sched_barrier(0) after the load batch kept from R8: all 8 loads
//    outstanding when the first FMA is scheduled.
__global__ void __launch_bounds__(256)
weighted_sum_kernel(const f32x4* __restrict__ data,
                    const unsigned long long* __restrict__ rowmask,
                    const longlong2* __restrict__ colmask2,
                    float* __restrict__ out) {
    int idx = blockIdx.x * 256 + threadIdx.x;     // 0 .. TSPLIT*SLICE4-1
    int tz  = (idx >= SLICE4) ? 1 : 0;            // which T-half
    int pos = idx - tz * SLICE4;                  // position within slice
    int y  = pos / W4;
    int x4 = pos - y * W4;

    // Mask loads issued first; their latency overlaps the data-load batch.
    unsigned long long rm = rowmask[y];
    longlong2 c01 = colmask2[x4 * 2 + 0];         // colmask[4*x4 + 0,1]
    longlong2 c23 = colmask2[x4 * 2 + 1];         // colmask[4*x4 + 2,3]

    const f32x4* p = data + tz * (TPT * SLICE4) + pos;
    f32x4 v[TPT];
#pragma unroll
    for (int t = 0; t < TPT; ++t)
        v[t] = __builtin_nontemporal_load(p + t * SLICE4);

    // Hard scheduling fence: nothing moves across. All 8 loads are
    // outstanding when the first consumer below is scheduled.
    __builtin_amdgcn_sched_barrier(0);

    float w0 = (float)__popcll(rm & (unsigned long long)c01.x);
    float w1 = (float)__popcll(rm & (unsigned long long)c01.y);
    float w2 = (float)__popcll(rm & (unsigned long long)c23.x);
    float w3 = (float)__popcll(rm & (unsigned long long)c23.y);

    float a0 = 0.f, a1 = 0.f, a2 = 0.f, a3 = 0.f;
#pragma unroll
    for (int t = 0; t < TPT; t += 4) {
        a0 += v[t + 0].x * w0 + v[t + 0].y * w1 + v[t + 0].z * w2 + v[t + 0].w * w3;
        a1 += v[t + 1].x * w0 + v[t + 1].y * w1 + v[t + 1].z * w2 + v[t + 1].w * w3;
        a2 += v[t + 2].x * w0 + v[t + 2].y * w1 + v[t + 2].z * w2 + v[t + 2].w * w3;
        a3 += v[t + 3].x * w0 + v[t + 3].y * w1 + v[t + 3].z * w2 + v[t + 3].w * w3;
    }
    float acc = (a0 + a1) + (a2 + a3);

    // 64-lane wave shuffle reduction -> LDS -> one atomic per block.
#pragma unroll
    for (int off = 32; off > 0; off >>= 1)
        acc += __shfl_down(acc, off, 64);

    __shared__ float wsum[4];
    int lane = threadIdx.x & 63;
    int wid  = threadIdx.x >> 6;
    if (lane == 0) wsum[wid] = acc;
    __syncthreads();
    if (threadIdx.x == 0) {
        float s = (wsum[0] + wsum[1]) + (wsum[2] + wsum[3]);
        atomicAdd(out, s);
    }
}

extern "C" void kernel_launch(void* const* d_in, const int* in_sizes, int n_in,
                              void* d_out, int out_size, void* d_ws, size_t ws_size,
                              hipStream_t stream) {
    const float* data = (const float*)d_in[0];        // (T,H,W) float32
    const int* boxes  = (const int*)d_in[1];          // (N,4) int32
    float* out = (float*)d_out;                       // scalar (poisoned)

    // d_ws: rowmask[1280] u64, colmask[1280] u64 (colmask 16B-aligned).
    unsigned long long* rowmask = (unsigned long long*)d_ws;
    unsigned long long* colmask = rowmask + HH;

    build_masks_kernel<<<10, 256, 0, stream>>>(boxes, rowmask, colmask, out);
    weighted_sum_kernel<<<(TSPLIT * SLICE4) / 256, 256, 0, stream>>>(
        (const f32x4*)data, rowmask, (const longlong2*)colmask, out);
}

// Round 2
// 157.860 us; speedup vs baseline: 1.1253x; 1.1253x over previous
//
#include <hip/hip_runtime.h>

// Problem constants: T=16, H=1280, W=1280, N=64 boxes.
#define TT 16
#define HH 1280
#define WW 1280
#define NBOX 64
#define W4 (WW / 4)             // 320 float4 per row
#define SLICE4 (HH * W4)        // 409600 float4 per T-slice

// K1: build row/col membership bitmasks (one bit per box) in d_ws, and
// zero the output scalar (replaces the separate 4-byte hipMemsetAsync —
// stream order guarantees this lands before any K2 atomicAdd).
__global__ void build_masks_kernel(const int* __restrict__ boxes,
                                   unsigned long long* __restrict__ rowmask,
                                   unsigned long long* __restrict__ colmask,
                                   float* __restrict__ out) {
    __shared__ int bx1[NBOX], by1[NBOX], bx2[NBOX], by2[NBOX];
    int tid = threadIdx.x;
    if (tid < NBOX) {
        int4 b = ((const int4*)boxes)[tid];   // (x1, y1, x2, y2)
        bx1[tid] = b.x; by1[tid] = b.y; bx2[tid] = b.z; by2[tid] = b.w;
    }
    if (blockIdx.x == 0 && tid == 0) *out = 0.f;
    __syncthreads();
    int g = blockIdx.x * 256 + tid;           // 0..2559
    if (g < HH) {
        int y = g;
        unsigned long long m = 0ull;
#pragma unroll
        for (int b = 0; b < NBOX; ++b)
            if (by1[b] <= y && y < by2[b]) m |= (1ull << b);
        rowmask[y] = m;
    } else if (g < HH + WW) {
        int x = g - HH;
        unsigned long long m = 0ull;
#pragma unroll
        for (int b = 0; b < NBOX; ++b)
            if (bx1[b] <= x && x < bx2[b]) m |= (1ull << b);
        colmask[x] = m;
    }
}

// K2: R8 structure + FORCED memory-level parallelism (known-good R0 form).
// 16-deep load batch per thread; sched_barrier(0) forbids the scheduler
// from sinking loads toward uses, so the first FMA waits at vmcnt(15)
// with 15 loads in flight. Plain (temporal) loads: the 105 MB input fits
// the 256 MiB Infinity Cache and is re-read every timed iteration — R1
// proved nontemporal loads cost ~20 us by defeating L3 residency.
__global__ void __launch_bounds__(256)
weighted_sum_kernel(const float4* __restrict__ data,
                    const unsigned long long* __restrict__ rowmask,
                    const longlong2* __restrict__ colmask2,
                    float* __restrict__ out) {
    int idx = blockIdx.x * 256 + threadIdx.x;     // exactly SLICE4 threads
    int y  = idx / W4;
    int x4 = idx - y * W4;

    // Mask loads issued first; their latency overlaps the data-load batch.
    unsigned long long rm = rowmask[y];
    longlong2 c01 = colmask2[x4 * 2 + 0];         // colmask[4*x4 + 0,1]
    longlong2 c23 = colmask2[x4 * 2 + 1];         // colmask[4*x4 + 2,3]

    const float4* p = data + idx;
    float4 v[TT];
#pragma unroll
    for (int t = 0; t < TT; ++t)
        v[t] = p[t * SLICE4];                     // 16 independent dwordx4

    // Hard scheduling fence: nothing moves across. All 16 loads are
    // outstanding when the first consumer below is scheduled.
    __builtin_amdgcn_sched_barrier(0);

    float w0 = (float)__popcll(rm & (unsigned long long)c01.x);
    float w1 = (float)__popcll(rm & (unsigned long long)c01.y);
    float w2 = (float)__popcll(rm & (unsigned long long)c23.x);
    float w3 = (float)__popcll(rm & (unsigned long long)c23.y);

    float a0 = 0.f, a1 = 0.f, a2 = 0.f, a3 = 0.f;
#pragma unroll
    for (int t = 0; t < TT; t += 4) {
        a0 += v[t + 0].x * w0 + v[t + 0].y * w1 + v[t + 0].z * w2 + v[t + 0].w * w3;
        a1 += v[t + 1].x * w0 + v[t + 1].y * w1 + v[t + 1].z * w2 + v[t + 1].w * w3;
        a2 += v[t + 2].x * w0 + v[t + 2].y * w1 + v[t + 2].z * w2 + v[t + 2].w * w3;
        a3 += v[t + 3].x * w0 + v[t + 3].y * w1 + v[t + 3].z * w2 + v[t + 3].w * w3;
    }
    float acc = (a0 + a1) + (a2 + a3);

    // 64-lane wave shuffle reduction -> LDS -> one atomic per block.
#pragma unroll
    for (int off = 32; off > 0; off >>= 1)
        acc += __shfl_down(acc, off, 64);

    __shared__ float wsum[4];
    int lane = threadIdx.x & 63;
    int wid  = threadIdx.x >> 6;
    if (lane == 0) wsum[wid] = acc;
    __syncthreads();
    if (threadIdx.x == 0) {
        float s = (wsum[0] + wsum[1]) + (wsum[2] + wsum[3]);
        atomicAdd(out, s);
    }
}

extern "C" void kernel_launch(void* const* d_in, const int* in_sizes, int n_in,
                              void* d_out, int out_size, void* d_ws, size_t ws_size,
                              hipStream_t stream) {
    const float* data = (const float*)d_in[0];        // (T,H,W) float32
    const int* boxes  = (const int*)d_in[1];          // (N,4) int32
    float* out = (float*)d_out;                       // scalar (poisoned)

    // d_ws: rowmask[1280] u64, colmask[1280] u64 (colmask 16B-aligned).
    unsigned long long* rowmask = (unsigned long long*)d_ws;
    unsigned long long* colmask = rowmask + HH;

    build_masks_kernel<<<10, 256, 0, stream>>>(boxes, rowmask, colmask, out);
    weighted_sum_kernel<<<SLICE4 / 256, 256, 0, stream>>>(
        (const float4*)data, rowmask, (const longlong2*)colmask, out);
}

// Round 3
// 154.789 us; speedup vs baseline: 1.1476x; 1.0198x over previous
//
#include <hip/hip_runtime.h>

// Problem constants: T=16, H=1280, W=1280, N=64 boxes.
#define TT 16
#define HH 1280
#define WW 1280
#define NBOX 64
#define W4 (WW / 4)             // 320 float4 per row
#define SLICE4 (HH * W4)        // 409600 float4 per T-slice

// K1: build row/col membership bitmasks (one bit per box) in d_ws, and
// zero the output scalar (fused memset; stream order guarantees it lands
// before any K2 atomicAdd).
__global__ void build_masks_kernel(const int* __restrict__ boxes,
                                   unsigned long long* __restrict__ rowmask,
                                   unsigned long long* __restrict__ colmask,
                                   float* __restrict__ out) {
    __shared__ int bx1[NBOX], by1[NBOX], bx2[NBOX], by2[NBOX];
    int tid = threadIdx.x;
    if (tid < NBOX) {
        int4 b = ((const int4*)boxes)[tid];   // (x1, y1, x2, y2)
        bx1[tid] = b.x; by1[tid] = b.y; bx2[tid] = b.z; by2[tid] = b.w;
    }
    if (blockIdx.x == 0 && tid == 0) *out = 0.f;
    __syncthreads();
    int g = blockIdx.x * 256 + tid;           // 0..2559
    if (g < HH) {
        int y = g;
        unsigned long long m = 0ull;
#pragma unroll
        for (int b = 0; b < NBOX; ++b)
            if (by1[b] <= y && y < by2[b]) m |= (1ull << b);
        rowmask[y] = m;
    } else if (g < HH + WW) {
        int x = g - HH;
        unsigned long long m = 0ull;
#pragma unroll
        for (int b = 0; b < NBOX; ++b)
            if (bx1[b] <= x && x < bx2[b]) m |= (1ull << b);
        colmask[x] = m;
    }
}

// K2: R8 structure + FORCED memory-level parallelism, occupancy-fixed.
// 16-deep load batch per thread; sched_barrier(0) keeps all 16 loads
// outstanding at the first consumer (previous-session evidence: without
// it the scheduler sinks loads and the kernel latency-plateaus).
// __launch_bounds__(256, 6): cap VGPR at 85 -> 6 blocks/CU -> 1536 of
// 1600 blocks resident (was 5/CU = 1280 resident, leaving a 320-block
// ~20.5 MB lockstep tail pass). Batch liveness is 64 VGPR; the t*SLICE4
// load offsets are wave-uniform (SGPR-addressable), so ~80 VGPR fits
// without spill. Plain temporal loads (R1: nontemporal cost ~20 us by
// defeating L3 residency across timed iterations).
__global__ void __launch_bounds__(256, 6)
weighted_sum_kernel(const float4* __restrict__ data,
                    const unsigned long long* __restrict__ rowmask,
                    const longlong2* __restrict__ colmask2,
                    float* __restrict__ out) {
    int idx = blockIdx.x * 256 + threadIdx.x;     // exactly SLICE4 threads
    int y  = idx / W4;
    int x4 = idx - y * W4;

    // Mask loads issued first; their latency overlaps the data-load batch.
    unsigned long long rm = rowmask[y];
    longlong2 c01 = colmask2[x4 * 2 + 0];         // colmask[4*x4 + 0,1]
    longlong2 c23 = colmask2[x4 * 2 + 1];         // colmask[4*x4 + 2,3]

    const float4* p = data + idx;
    float4 v[TT];
#pragma unroll
    for (int t = 0; t < TT; ++t)
        v[t] = p[t * SLICE4];                     // 16 independent dwordx4

    // Hard scheduling fence: nothing moves across. All 16 loads are
    // outstanding when the first consumer below is scheduled.
    __builtin_amdgcn_sched_barrier(0);

    float w0 = (float)__popcll(rm & (unsigned long long)c01.x);
    float w1 = (float)__popcll(rm & (unsigned long long)c01.y);
    float w2 = (float)__popcll(rm & (unsigned long long)c23.x);
    float w3 = (float)__popcll(rm & (unsigned long long)c23.y);

    float a0 = 0.f, a1 = 0.f, a2 = 0.f, a3 = 0.f;
#pragma unroll
    for (int t = 0; t < TT; t += 4) {
        a0 += v[t + 0].x * w0 + v[t + 0].y * w1 + v[t + 0].z * w2 + v[t + 0].w * w3;
        a1 += v[t + 1].x * w0 + v[t + 1].y * w1 + v[t + 1].z * w2 + v[t + 1].w * w3;
        a2 += v[t + 2].x * w0 + v[t + 2].y * w1 + v[t + 2].z * w2 + v[t + 2].w * w3;
        a3 += v[t + 3].x * w0 + v[t + 3].y * w1 + v[t + 3].z * w2 + v[t + 3].w * w3;
    }
    float acc = (a0 + a1) + (a2 + a3);

    // 64-lane wave shuffle reduction -> LDS -> one atomic per block.
#pragma unroll
    for (int off = 32; off > 0; off >>= 1)
        acc += __shfl_down(acc, off, 64);

    __shared__ float wsum[4];
    int lane = threadIdx.x & 63;
    int wid  = threadIdx.x >> 6;
    if (lane == 0) wsum[wid] = acc;
    __syncthreads();
    if (threadIdx.x == 0) {
        float s = (wsum[0] + wsum[1]) + (wsum[2] + wsum[3]);
        atomicAdd(out, s);
    }
}

extern "C" void kernel_launch(void* const* d_in, const int* in_sizes, int n_in,
                              void* d_out, int out_size, void* d_ws, size_t ws_size,
                              hipStream_t stream) {
    const float* data = (const float*)d_in[0];        // (T,H,W) float32
    const int* boxes  = (const int*)d_in[1];          // (N,4) int32
    float* out = (float*)d_out;                       // scalar (poisoned)

    // d_ws: rowmask[1280] u64, colmask[1280] u64 (colmask 16B-aligned).
    unsigned long long* rowmask = (unsigned long long*)d_ws;
    unsigned long long* colmask = rowmask + HH;

    build_masks_kernel<<<10, 256, 0, stream>>>(boxes, rowmask, colmask, out);
    weighted_sum_kernel<<<SLICE4 / 256, 256, 0, stream>>>(
        (const float4*)data, rowmask, (const longlong2*)colmask, out);
}